// Round 17
// baseline (101.231 us; speedup 1.0000x reference)
//
#include <hip/hip_runtime.h>
#include <stdint.h>

#define D 4096
#define RANK 8
#define ALPHA 1.5f
#define BETA 0.5f
#define SUM_TIMESTEPS 28000
#define K_TOP 64
#define NBINS 1024

typedef float f32x4 __attribute__((ext_vector_type(4)));

// ws layout (bytes):
//   [0, 256)            : u32 hdr[]: [4]=flag (written unconditionally each call)
//   [256, 256+8K)       : u32 gcnt[2][NBINS]   (zeroed by k_pass_max each call)
//   [8448, 8448+16K)    : u64 gsum[2][NBINS]   (zeroed by k_pass_max each call)
//   [24832, 24832+2K)   : u32 bmax[2][256]     (written unconditionally each call)
//   [26880, +256K)      : f32 t[8192][8]       (written unconditionally each call)
#define WS_GCNT_OFF 256
#define WS_GSUM_OFF (256 + 2 * NBINS * 4)
#define WS_BMAX_OFF (WS_GSUM_OFF + 2 * NBINS * 8)
#define WS_T_OFF    (WS_BMAX_OFF + 2048)

// fixed-point scale: 2^38 / max  (sum of 16.7M maximal values still < 2^62)
#define FIX_NUM 2.74877906944e11f
#define FIX_INV 3.637978807091713e-12   // 2^-38

__device__ __forceinline__ float dot4v(f32x4 a, f32x4 b) {
    return fmaf(a.x, b.x, fmaf(a.y, b.y, fmaf(a.z, b.z, a.w * b.w)));
}

// ---------------------------------------------------------------------------
// Pass 1: per-block max of |wa@wb| -> bmax[mat][bid]. wa slice staged in LDS.
// Zeroes gcnt/gsum for the NEXT kernel. grid (256, 2), block 256.
// ---------------------------------------------------------------------------
__global__ __launch_bounds__(256) void k_pass_max(
    const float* __restrict__ wa1, const float* __restrict__ wb1,
    const float* __restrict__ wa2, const float* __restrict__ wb2,
    unsigned* __restrict__ gz, unsigned* __restrict__ bmax) {
    const int tid = threadIdx.x;
    const int mat = blockIdx.y;
    const int bid = blockIdx.x;
    // zero gcnt/gsum stripes (consumed by the NEXT kernel, so no race)
    if (mat == 0 && tid < 24) gz[bid * 24 + tid] = 0u;

    const float* __restrict__ wa = mat ? wa2 : wa1;
    const float* __restrict__ wb = mat ? wb2 : wb1;
    const int i0 = (bid & 3) * 1024 + tid * 4;
    const int obase = (bid >> 2) * 64;

    __shared__ float was[64][8];  // 2 KB wa slice
    if (tid < 128)
        ((f32x4*)was)[tid] = ((const f32x4*)(wa + (size_t)obase * RANK))[tid];

    f32x4 wbv[RANK];
#pragma unroll
    for (int r = 0; r < RANK; ++r)
        wbv[r] = *(const f32x4*)(wb + r * D + i0);
    __syncthreads();

    float vmax = 0.f;
#pragma unroll 4
    for (int oo = 0; oo < 64; ++oo) {
        const f32x4 w03 = *(const f32x4*)&was[oo][0];  // LDS broadcast
        const f32x4 w47 = *(const f32x4*)&was[oo][4];
        f32x4 s = {0.f, 0.f, 0.f, 0.f};
        const float a[8] = {w03.x, w03.y, w03.z, w03.w, w47.x, w47.y, w47.z, w47.w};
#pragma unroll
        for (int r = 0; r < RANK; ++r) {
            s.x = fmaf(a[r], wbv[r].x, s.x);
            s.y = fmaf(a[r], wbv[r].y, s.y);
            s.z = fmaf(a[r], wbv[r].z, s.z);
            s.w = fmaf(a[r], wbv[r].w, s.w);
        }
        vmax = fmaxf(vmax, fmaxf(fmaxf(fabsf(s.x), fabsf(s.y)),
                                 fmaxf(fabsf(s.z), fabsf(s.w))));
    }
    for (int off = 32; off; off >>= 1)
        vmax = fmaxf(vmax, __shfl_xor(vmax, off, 64));
    __shared__ float smax[4];
    const int wave = tid >> 6, lane = tid & 63;
    if (lane == 0) smax[wave] = vmax;
    __syncthreads();
    if (tid == 0) {
        float m = fmaxf(fmaxf(smax[0], smax[1]), fmaxf(smax[2], smax[3]));
        bmax[mat * 256 + bid] = __float_as_uint(m);  // unconditional write
    }
}

// ---------------------------------------------------------------------------
// helper: block-level max over 256 bmax entries (block must be >=256 thr)
// ---------------------------------------------------------------------------
__device__ __forceinline__ float block_max256(const unsigned* __restrict__ bmax,
                                              int mat, int tid, float* redm) {
    const int wave = tid >> 6, lane = tid & 63;
    float m = 0.f;
    if (tid < 256) m = __uint_as_float(bmax[mat * 256 + tid]);
    for (int off = 32; off; off >>= 1)
        m = fmaxf(m, __shfl_xor(m, off, 64));
    if (tid < 256 && lane == 0) redm[wave] = m;
    __syncthreads();
    return fmaxf(fmaxf(redm[0], redm[1]), fmaxf(redm[2], redm[3]));
}

// ---------------------------------------------------------------------------
// Pass 2: histogram all |elem| >= 0.5*max. Counts u32, sums u64 fixed-point
// (order-independent integer atomics -> bit-deterministic across replays).
// wa slice staged in LDS. grid (256, 2), block 256.
// ---------------------------------------------------------------------------
__global__ __launch_bounds__(256) void k_pass_hist(
    const float* __restrict__ wa1, const float* __restrict__ wb1,
    const float* __restrict__ wa2, const float* __restrict__ wb2,
    const unsigned* __restrict__ bmax,
    unsigned* __restrict__ gcnt, unsigned long long* __restrict__ gsum) {
    __shared__ unsigned lcnt[NBINS];
    __shared__ unsigned long long lsum[NBINS];
    __shared__ float was[64][8];
    __shared__ float redm[4];
    const int tid = threadIdx.x;
    const int mat = blockIdx.y;
    for (int b = tid; b < NBINS; b += 256) { lcnt[b] = 0u; lsum[b] = 0ull; }

    const float* __restrict__ wa = mat ? wa2 : wa1;
    const float* __restrict__ wb = mat ? wb2 : wb1;
    const int i0 = (blockIdx.x & 3) * 1024 + tid * 4;
    const int obase = (blockIdx.x >> 2) * 64;
    if (tid < 128)
        ((f32x4*)was)[tid] = ((const f32x4*)(wa + (size_t)obase * RANK))[tid];

    // (block_max256 contains the needed barrier)
    const float M = block_max256(bmax, mat, tid, redm);
    const float T = 0.5f * M;
    const float fix = FIX_NUM / M;
    const unsigned bitsT = __float_as_uint(T);

    f32x4 wbv[RANK];
#pragma unroll
    for (int r = 0; r < RANK; ++r)
        wbv[r] = *(const f32x4*)(wb + r * D + i0);

#pragma unroll 2
    for (int oo = 0; oo < 64; ++oo) {
        const f32x4 w03 = *(const f32x4*)&was[oo][0];
        const f32x4 w47 = *(const f32x4*)&was[oo][4];
        f32x4 s = {0.f, 0.f, 0.f, 0.f};
        const float a[8] = {w03.x, w03.y, w03.z, w03.w, w47.x, w47.y, w47.z, w47.w};
#pragma unroll
        for (int r = 0; r < RANK; ++r) {
            s.x = fmaf(a[r], wbv[r].x, s.x);
            s.y = fmaf(a[r], wbv[r].y, s.y);
            s.z = fmaf(a[r], wbv[r].z, s.z);
            s.w = fmaf(a[r], wbv[r].w, s.w);
        }
        const float av[4] = {fabsf(s.x), fabsf(s.y), fabsf(s.z), fabsf(s.w)};
#pragma unroll
        for (int j = 0; j < 4; ++j) {
            if (av[j] >= T) {
                unsigned k = (__float_as_uint(av[j]) - bitsT) >> 13;
                if (k > NBINS - 1u) k = NBINS - 1u;
                atomicAdd(&lcnt[k], 1u);
                atomicAdd(&lsum[k], (unsigned long long)(av[j] * fix));
            }
        }
    }
    __syncthreads();
    unsigned* __restrict__ gc = gcnt + (size_t)mat * NBINS;
    unsigned long long* __restrict__ gs = gsum + (size_t)mat * NBINS;
    for (int b = tid; b < NBINS; b += 256) {
        unsigned c = lcnt[b];
        if (c) {
            atomicAdd(&gc[b], c);
            atomicAdd(&gs[b], lsum[b]);
        }
    }
}

// ---------------------------------------------------------------------------
// Pass 3: one block, 1024 threads; suffix-scan histogram (integer, exact),
// top-64 cutoff, flag. Fully deterministic.
// ---------------------------------------------------------------------------
__global__ __launch_bounds__(1024) void k_select(
    unsigned* __restrict__ hdr, const unsigned* __restrict__ bmax,
    const unsigned* __restrict__ gcnt, const unsigned long long* __restrict__ gsum,
    const int* __restrict__ tsp) {
    __shared__ unsigned sc[NBINS];
    __shared__ unsigned long long ss[NBINS];
    __shared__ float res[2];
    __shared__ float Ms[2];
    __shared__ float redm[4];
    __shared__ int sB;
    const int b = threadIdx.x;

    for (int mat = 0; mat < 2; ++mat) {
        float M = block_max256(bmax, mat, b, redm);
        if (b == 0) Ms[mat] = M;
        __syncthreads();
    }

    for (int mat = 0; mat < 2; ++mat) {
        if (b == 0) sB = -1;
        const unsigned c0 = gcnt[(size_t)mat * NBINS + b];
        const unsigned long long s0 = gsum[(size_t)mat * NBINS + b];
        __syncthreads();           // previous iteration's readers done
        sc[b] = c0;
        ss[b] = s0;
        __syncthreads();
        // Hillis-Steele suffix scan (integer adds: exact, order-independent)
        for (int step = 1; step < NBINS; step <<= 1) {
            unsigned c2 = 0u; unsigned long long s2 = 0ull;
            if (b + step < NBINS) { c2 = sc[b + step]; s2 = ss[b + step]; }
            __syncthreads();
            sc[b] += c2;
            ss[b] += s2;
            __syncthreads();
        }
        if (sc[b] >= K_TOP && (b == NBINS - 1 || sc[b + 1] < K_TOP)) sB = b;
        __syncthreads();
        if (b == 0) {
            const double inv = (double)Ms[mat] * FIX_INV;  // decode units -> value
            float total;
            if (sB < 0) {
                total = (float)((double)ss[0] * inv);
            } else {
                const int B = sB;
                const unsigned cAbove = (B + 1 < NBINS) ? sc[B + 1] : 0u;
                const unsigned long long sAbove = (B + 1 < NBINS) ? ss[B + 1] : 0ull;
                const unsigned cb = sc[B] - cAbove;
                const unsigned long long sb = ss[B] - sAbove;
                const unsigned need = K_TOP - cAbove;
                total = (float)((double)sAbove * inv)
                      + (float)((double)sb * inv) * ((float)need / (float)cb);
            }
            res[mat] = total;
        }
        __syncthreads();
    }
    if (b == 0) {
        const int tr = (*tsp) % SUM_TIMESTEPS;
        const float scale = fmodf(ALPHA * (float)tr / (float)SUM_TIMESTEPS + BETA, ALPHA);
        const float temp_ratio = res[0] / (res[1] * scale);  // AVG_RATIO = 1.0
        hdr[4] = (temp_ratio > 1.0f) ? 1u : 0u;              // 1 -> matrix1
    }
}

// ---------------------------------------------------------------------------
// Kernel T: R11 structure scaled to 32 ROWS/BLOCK (512 thr, 8 waves,
// grid 256) — the wb staging request traffic drops 134 MB -> 33 MB, so the
// load path moves 167 MB total instead of 268 MB. Per quarter: stage 32 KB
// (4 sreg each), issue each wave's 16 nt h loads into registers BEFORE the
// ds_write+barrier, compute from registers + LDS broadcasts.
// ---------------------------------------------------------------------------
__global__ __launch_bounds__(512) void k_t(
    const float* __restrict__ h,
    const float* __restrict__ wb1, const float* __restrict__ wb2,
    const unsigned* __restrict__ hdr,
    float* __restrict__ t) {
    const int tid = threadIdx.x;
    const int wave = tid >> 6, lane = tid & 63;
    const float* __restrict__ wb = hdr[4] ? wb1 : wb2;
    const size_t m0 = (size_t)blockIdx.x * 32;
    const int r0w = wave * 4;  // this wave's 4 local rows

    __shared__ float wbs[RANK][1024];  // 32 KB: quarter of wb

    float acc[4][RANK];
#pragma unroll
    for (int row = 0; row < 4; ++row)
#pragma unroll
        for (int r = 0; r < RANK; ++r) acc[row][r] = 0.f;

    const f32x4* __restrict__ src = (const f32x4*)wb;  // row stride 1024 f32x4
    f32x4* __restrict__ dst = (f32x4*)wbs;

    for (int q = 0; q < 4; ++q) {
        __syncthreads();  // previous quarter's readers done
        // 1) issue stage loads (4 x f32x4, CACHED: reused by 256 blocks)
        f32x4 sreg[4];
#pragma unroll
        for (int s = 0; s < 4; ++s) {
            const int j = s * 512 + tid;   // [0, 2048)
            sreg[s] = src[(j >> 8) * 1024 + q * 256 + (j & 255)];
        }
        // 2) issue the quarter's 16 h loads, NONTEMPORAL (use-once stream)
        f32x4 hv[4][4];  // [k][row]
#pragma unroll
        for (int k = 0; k < 4; ++k)
#pragma unroll
            for (int row = 0; row < 4; ++row)
                hv[k][row] = __builtin_nontemporal_load(
                    (const f32x4*)(h + (m0 + r0w + row) * D
                                   + q * 1024 + k * 256 + lane * 4));
        // 3) LDS write (waits only the stage loads; h stays in flight)
#pragma unroll
        for (int s = 0; s < 4; ++s) dst[s * 512 + tid] = sreg[s];
        __syncthreads();
        // 4) compute from registers + LDS broadcasts
#pragma unroll
        for (int k = 0; k < 4; ++k) {
            const int il = k * 256 + lane * 4;
            f32x4 wbv[RANK];
#pragma unroll
            for (int r = 0; r < RANK; ++r)
                wbv[r] = *(const f32x4*)&wbs[r][il];
#pragma unroll
            for (int row = 0; row < 4; ++row)
#pragma unroll
                for (int r = 0; r < RANK; ++r)
                    acc[row][r] = fmaf(hv[k][row].x, wbv[r].x,
                                  fmaf(hv[k][row].y, wbv[r].y,
                                  fmaf(hv[k][row].z, wbv[r].z,
                                  fmaf(hv[k][row].w, wbv[r].w, acc[row][r]))));
        }
    }

    // butterfly reduce over lanes; lane0 stores t (tiny write)
#pragma unroll
    for (int row = 0; row < 4; ++row)
#pragma unroll
        for (int r = 0; r < RANK; ++r)
#pragma unroll
            for (int off = 32; off; off >>= 1)
                acc[row][r] += __shfl_xor(acc[row][r], off, 64);
    if (lane == 0) {
#pragma unroll
        for (int row = 0; row < 4; ++row) {
            const f32x4 v0 = {acc[row][0], acc[row][1], acc[row][2], acc[row][3]};
            const f32x4 v1 = {acc[row][4], acc[row][5], acc[row][6], acc[row][7]};
            f32x4* __restrict__ dt = (f32x4*)(t + (m0 + r0w + row) * RANK);
            dt[0] = v0; dt[1] = v1;
        }
    }
}

// ---------------------------------------------------------------------------
// Kernel O: out[m][o] = sum_r t[m][r] * wa[o][r]. Plain stores (R16-best).
// 16 rows/block -> 2048 blocks: more store concurrency (fillBuffer's 7 TB/s
// comes with a huge trivial grid). wa re-reads (67 MB) ride the idle load
// path of this write-dominated kernel.
// ---------------------------------------------------------------------------
__global__ __launch_bounds__(256) void k_o(
    const float* __restrict__ t,
    const float* __restrict__ wa1, const float* __restrict__ wa2,
    const unsigned* __restrict__ hdr,
    float* __restrict__ out) {
    const int tid = threadIdx.x;
    const int wave = tid >> 6, lane = tid & 63;
    const float* __restrict__ wa = hdr[4] ? wa1 : wa2;
    const int cslice = blockIdx.x & 3;               // which 1024-col slice
    const size_t m0 = (size_t)(blockIdx.x >> 2) * 16;
    const int o0 = cslice * 1024 + wave * 256 + lane * 4;

    __shared__ float ts[16][8];  // 512 B t tile
    if (tid < 32)
        ((f32x4*)ts)[tid] = *(const f32x4*)(t + m0 * RANK + tid * 4);

    f32x4 A[8];  // wa for this lane's 4 cols: A[2j]=col(o0+j) r0..3, A[2j+1]=r4..7
#pragma unroll
    for (int j = 0; j < 8; ++j)
        A[j] = *(const f32x4*)(wa + (size_t)o0 * RANK + j * 4);
    __syncthreads();

#pragma unroll 4
    for (int row = 0; row < 16; ++row) {
        const f32x4 t03 = *(const f32x4*)&ts[row][0];
        const f32x4 t47 = *(const f32x4*)&ts[row][4];
        f32x4 ov;
        ov.x = dot4v(A[0], t03) + dot4v(A[1], t47);
        ov.y = dot4v(A[2], t03) + dot4v(A[3], t47);
        ov.z = dot4v(A[4], t03) + dot4v(A[5], t47);
        ov.w = dot4v(A[6], t03) + dot4v(A[7], t47);
        *(f32x4*)(out + (m0 + row) * D + o0) = ov;  // plain store
    }
}

extern "C" void kernel_launch(void* const* d_in, const int* in_sizes, int n_in,
                              void* d_out, int out_size, void* d_ws, size_t ws_size,
                              hipStream_t stream) {
    const float* h   = (const float*)d_in[0];
    const float* wa1 = (const float*)d_in[1];
    const float* wb1 = (const float*)d_in[2];
    const float* wa2 = (const float*)d_in[3];
    const float* wb2 = (const float*)d_in[4];
    const int*   ts  = (const int*)d_in[5];
    float* out = (float*)d_out;

    const int rows = in_sizes[0] / D;  // 8192

    unsigned* hdr  = (unsigned*)d_ws;
    unsigned* gcnt = (unsigned*)((char*)d_ws + WS_GCNT_OFF);
    unsigned long long* gsum = (unsigned long long*)((char*)d_ws + WS_GSUM_OFF);
    unsigned* bmax = (unsigned*)((char*)d_ws + WS_BMAX_OFF);
    float*    tbuf = (float*)((char*)d_ws + WS_T_OFF);

    hipLaunchKernelGGL(k_pass_max, dim3(256, 2), dim3(256), 0, stream,
                       wa1, wb1, wa2, wb2, gcnt, bmax);
    hipLaunchKernelGGL(k_pass_hist, dim3(256, 2), dim3(256), 0, stream,
                       wa1, wb1, wa2, wb2, bmax, gcnt, gsum);
    hipLaunchKernelGGL(k_select, dim3(1), dim3(1024), 0, stream,
                       hdr, bmax, gcnt, gsum, ts);
    hipLaunchKernelGGL(k_t, dim3(rows / 32), dim3(512), 0, stream,
                       h, wb1, wb2, hdr, tbuf);
    hipLaunchKernelGGL(k_o, dim3(4 * (rows / 16)), dim3(256), 0, stream,
                       tbuf, wa1, wa2, hdr, out);
}

// Round 18
// 98.409 us; speedup vs baseline: 1.0287x; 1.0287x over previous
//
#include <hip/hip_runtime.h>
#include <stdint.h>

#define D 4096
#define RANK 8
#define ALPHA 1.5f
#define BETA 0.5f
#define SUM_TIMESTEPS 28000
#define K_TOP 64
#define NBINS 1024

typedef float f32x4 __attribute__((ext_vector_type(4)));

// ws layout (bytes):
//   [0, 256)            : u32 hdr[]: [4]=flag (written unconditionally each call)
//   [256, 256+8K)       : u32 gcnt[2][NBINS]   (zeroed by k_pass_max each call)
//   [8448, 8448+16K)    : u64 gsum[2][NBINS]   (zeroed by k_pass_max each call)
//   [24832, 24832+2K)   : u32 bmax[2][256]     (written unconditionally each call)
//   [26880, +256K)      : f32 t[8192][8]       (written unconditionally each call)
#define WS_GCNT_OFF 256
#define WS_GSUM_OFF (256 + 2 * NBINS * 4)
#define WS_BMAX_OFF (WS_GSUM_OFF + 2 * NBINS * 8)
#define WS_T_OFF    (WS_BMAX_OFF + 2048)

// fixed-point scale: 2^38 / max  (sum of 16.7M maximal values still < 2^62)
#define FIX_NUM 2.74877906944e11f
#define FIX_INV 3.637978807091713e-12   // 2^-38

__device__ __forceinline__ float dot4v(f32x4 a, f32x4 b) {
    return fmaf(a.x, b.x, fmaf(a.y, b.y, fmaf(a.z, b.z, a.w * b.w)));
}

// ---------------------------------------------------------------------------
// Pass 1: per-block max of |wa@wb| -> bmax[mat][bid]. wa slice staged in LDS.
// Zeroes gcnt/gsum for the NEXT kernel. grid (256, 2), block 256.
// ---------------------------------------------------------------------------
__global__ __launch_bounds__(256) void k_pass_max(
    const float* __restrict__ wa1, const float* __restrict__ wb1,
    const float* __restrict__ wa2, const float* __restrict__ wb2,
    unsigned* __restrict__ gz, unsigned* __restrict__ bmax) {
    const int tid = threadIdx.x;
    const int mat = blockIdx.y;
    const int bid = blockIdx.x;
    // zero gcnt/gsum stripes (consumed by the NEXT kernel, so no race)
    if (mat == 0 && tid < 24) gz[bid * 24 + tid] = 0u;

    const float* __restrict__ wa = mat ? wa2 : wa1;
    const float* __restrict__ wb = mat ? wb2 : wb1;
    const int i0 = (bid & 3) * 1024 + tid * 4;
    const int obase = (bid >> 2) * 64;

    __shared__ float was[64][8];  // 2 KB wa slice
    if (tid < 128)
        ((f32x4*)was)[tid] = ((const f32x4*)(wa + (size_t)obase * RANK))[tid];

    f32x4 wbv[RANK];
#pragma unroll
    for (int r = 0; r < RANK; ++r)
        wbv[r] = *(const f32x4*)(wb + r * D + i0);
    __syncthreads();

    float vmax = 0.f;
#pragma unroll 4
    for (int oo = 0; oo < 64; ++oo) {
        const f32x4 w03 = *(const f32x4*)&was[oo][0];  // LDS broadcast
        const f32x4 w47 = *(const f32x4*)&was[oo][4];
        f32x4 s = {0.f, 0.f, 0.f, 0.f};
        const float a[8] = {w03.x, w03.y, w03.z, w03.w, w47.x, w47.y, w47.z, w47.w};
#pragma unroll
        for (int r = 0; r < RANK; ++r) {
            s.x = fmaf(a[r], wbv[r].x, s.x);
            s.y = fmaf(a[r], wbv[r].y, s.y);
            s.z = fmaf(a[r], wbv[r].z, s.z);
            s.w = fmaf(a[r], wbv[r].w, s.w);
        }
        vmax = fmaxf(vmax, fmaxf(fmaxf(fabsf(s.x), fabsf(s.y)),
                                 fmaxf(fabsf(s.z), fabsf(s.w))));
    }
    for (int off = 32; off; off >>= 1)
        vmax = fmaxf(vmax, __shfl_xor(vmax, off, 64));
    __shared__ float smax[4];
    const int wave = tid >> 6, lane = tid & 63;
    if (lane == 0) smax[wave] = vmax;
    __syncthreads();
    if (tid == 0) {
        float m = fmaxf(fmaxf(smax[0], smax[1]), fmaxf(smax[2], smax[3]));
        bmax[mat * 256 + bid] = __float_as_uint(m);  // unconditional write
    }
}

// ---------------------------------------------------------------------------
// helper: block-level max over 256 bmax entries (block must be >=256 thr)
// ---------------------------------------------------------------------------
__device__ __forceinline__ float block_max256(const unsigned* __restrict__ bmax,
                                              int mat, int tid, float* redm) {
    const int wave = tid >> 6, lane = tid & 63;
    float m = 0.f;
    if (tid < 256) m = __uint_as_float(bmax[mat * 256 + tid]);
    for (int off = 32; off; off >>= 1)
        m = fmaxf(m, __shfl_xor(m, off, 64));
    if (tid < 256 && lane == 0) redm[wave] = m;
    __syncthreads();
    return fmaxf(fmaxf(redm[0], redm[1]), fmaxf(redm[2], redm[3]));
}

// ---------------------------------------------------------------------------
// Pass 2: histogram all |elem| >= 0.5*max. Counts u32, sums u64 fixed-point
// (order-independent integer atomics -> bit-deterministic across replays).
// wa slice staged in LDS. grid (256, 2), block 256.
// ---------------------------------------------------------------------------
__global__ __launch_bounds__(256) void k_pass_hist(
    const float* __restrict__ wa1, const float* __restrict__ wb1,
    const float* __restrict__ wa2, const float* __restrict__ wb2,
    const unsigned* __restrict__ bmax,
    unsigned* __restrict__ gcnt, unsigned long long* __restrict__ gsum) {
    __shared__ unsigned lcnt[NBINS];
    __shared__ unsigned long long lsum[NBINS];
    __shared__ float was[64][8];
    __shared__ float redm[4];
    const int tid = threadIdx.x;
    const int mat = blockIdx.y;
    for (int b = tid; b < NBINS; b += 256) { lcnt[b] = 0u; lsum[b] = 0ull; }

    const float* __restrict__ wa = mat ? wa2 : wa1;
    const float* __restrict__ wb = mat ? wb2 : wb1;
    const int i0 = (blockIdx.x & 3) * 1024 + tid * 4;
    const int obase = (blockIdx.x >> 2) * 64;
    if (tid < 128)
        ((f32x4*)was)[tid] = ((const f32x4*)(wa + (size_t)obase * RANK))[tid];

    // (block_max256 contains the needed barrier)
    const float M = block_max256(bmax, mat, tid, redm);
    const float T = 0.5f * M;
    const float fix = FIX_NUM / M;
    const unsigned bitsT = __float_as_uint(T);

    f32x4 wbv[RANK];
#pragma unroll
    for (int r = 0; r < RANK; ++r)
        wbv[r] = *(const f32x4*)(wb + r * D + i0);

#pragma unroll 2
    for (int oo = 0; oo < 64; ++oo) {
        const f32x4 w03 = *(const f32x4*)&was[oo][0];
        const f32x4 w47 = *(const f32x4*)&was[oo][4];
        f32x4 s = {0.f, 0.f, 0.f, 0.f};
        const float a[8] = {w03.x, w03.y, w03.z, w03.w, w47.x, w47.y, w47.z, w47.w};
#pragma unroll
        for (int r = 0; r < RANK; ++r) {
            s.x = fmaf(a[r], wbv[r].x, s.x);
            s.y = fmaf(a[r], wbv[r].y, s.y);
            s.z = fmaf(a[r], wbv[r].z, s.z);
            s.w = fmaf(a[r], wbv[r].w, s.w);
        }
        const float av[4] = {fabsf(s.x), fabsf(s.y), fabsf(s.z), fabsf(s.w)};
#pragma unroll
        for (int j = 0; j < 4; ++j) {
            if (av[j] >= T) {
                unsigned k = (__float_as_uint(av[j]) - bitsT) >> 13;
                if (k > NBINS - 1u) k = NBINS - 1u;
                atomicAdd(&lcnt[k], 1u);
                atomicAdd(&lsum[k], (unsigned long long)(av[j] * fix));
            }
        }
    }
    __syncthreads();
    unsigned* __restrict__ gc = gcnt + (size_t)mat * NBINS;
    unsigned long long* __restrict__ gs = gsum + (size_t)mat * NBINS;
    for (int b = tid; b < NBINS; b += 256) {
        unsigned c = lcnt[b];
        if (c) {
            atomicAdd(&gc[b], c);
            atomicAdd(&gs[b], lsum[b]);
        }
    }
}

// ---------------------------------------------------------------------------
// Pass 3: one block, 1024 threads; suffix-scan histogram (integer, exact),
// top-64 cutoff, flag. Fully deterministic.
// ---------------------------------------------------------------------------
__global__ __launch_bounds__(1024) void k_select(
    unsigned* __restrict__ hdr, const unsigned* __restrict__ bmax,
    const unsigned* __restrict__ gcnt, const unsigned long long* __restrict__ gsum,
    const int* __restrict__ tsp) {
    __shared__ unsigned sc[NBINS];
    __shared__ unsigned long long ss[NBINS];
    __shared__ float res[2];
    __shared__ float Ms[2];
    __shared__ float redm[4];
    __shared__ int sB;
    const int b = threadIdx.x;

    for (int mat = 0; mat < 2; ++mat) {
        float M = block_max256(bmax, mat, b, redm);
        if (b == 0) Ms[mat] = M;
        __syncthreads();
    }

    for (int mat = 0; mat < 2; ++mat) {
        if (b == 0) sB = -1;
        const unsigned c0 = gcnt[(size_t)mat * NBINS + b];
        const unsigned long long s0 = gsum[(size_t)mat * NBINS + b];
        __syncthreads();           // previous iteration's readers done
        sc[b] = c0;
        ss[b] = s0;
        __syncthreads();
        // Hillis-Steele suffix scan (integer adds: exact, order-independent)
        for (int step = 1; step < NBINS; step <<= 1) {
            unsigned c2 = 0u; unsigned long long s2 = 0ull;
            if (b + step < NBINS) { c2 = sc[b + step]; s2 = ss[b + step]; }
            __syncthreads();
            sc[b] += c2;
            ss[b] += s2;
            __syncthreads();
        }
        if (sc[b] >= K_TOP && (b == NBINS - 1 || sc[b + 1] < K_TOP)) sB = b;
        __syncthreads();
        if (b == 0) {
            const double inv = (double)Ms[mat] * FIX_INV;  // decode units -> value
            float total;
            if (sB < 0) {
                total = (float)((double)ss[0] * inv);
            } else {
                const int B = sB;
                const unsigned cAbove = (B + 1 < NBINS) ? sc[B + 1] : 0u;
                const unsigned long long sAbove = (B + 1 < NBINS) ? ss[B + 1] : 0ull;
                const unsigned cb = sc[B] - cAbove;
                const unsigned long long sb = ss[B] - sAbove;
                const unsigned need = K_TOP - cAbove;
                total = (float)((double)sAbove * inv)
                      + (float)((double)sb * inv) * ((float)need / (float)cb);
            }
            res[mat] = total;
        }
        __syncthreads();
    }
    if (b == 0) {
        const int tr = (*tsp) % SUM_TIMESTEPS;
        const float scale = fmodf(ALPHA * (float)tr / (float)SUM_TIMESTEPS + BETA, ALPHA);
        const float temp_ratio = res[0] / (res[1] * scale);  // AVG_RATIO = 1.0
        hdr[4] = (temp_ratio > 1.0f) ? 1u : 0u;              // 1 -> matrix1
    }
}

// ---------------------------------------------------------------------------
// Kernel T: R16 structure, 16 ROWS/BLOCK (256 thr, 4 waves x 4 rows,
// grid 512 = 2 blocks/CU). Halves wb staging request traffic vs R16
// (134 -> 67 MB; load path total 268 -> 201 MB) while keeping >=2 blocks/CU
// so barrier drains overlap across blocks (R17's grid-256 had 1/CU: bad).
// Same per-wave shape as R9's replay-proven k_fused phase 1.
// ---------------------------------------------------------------------------
__global__ __launch_bounds__(256) void k_t(
    const float* __restrict__ h,
    const float* __restrict__ wb1, const float* __restrict__ wb2,
    const unsigned* __restrict__ hdr,
    float* __restrict__ t) {
    const int tid = threadIdx.x;
    const int wave = tid >> 6, lane = tid & 63;
    const float* __restrict__ wb = hdr[4] ? wb1 : wb2;
    const size_t m0 = (size_t)blockIdx.x * 16;
    const int r0w = wave * 4;  // this wave's 4 local rows

    __shared__ float wbs[RANK][1024];  // 32 KB: quarter of wb

    float acc[4][RANK];
#pragma unroll
    for (int row = 0; row < 4; ++row)
#pragma unroll
        for (int r = 0; r < RANK; ++r) acc[row][r] = 0.f;

    const f32x4* __restrict__ src = (const f32x4*)wb;  // row stride 1024 f32x4
    f32x4* __restrict__ dst = (f32x4*)wbs;

    for (int q = 0; q < 4; ++q) {
        __syncthreads();  // previous quarter's readers done
        // 1) issue stage loads (8 x f32x4, CACHED: reused by 512 blocks)
        f32x4 sreg[8];
#pragma unroll
        for (int s = 0; s < 8; ++s) {
            const int j = s * 256 + tid;   // [0, 2048)
            sreg[s] = src[(j >> 8) * 1024 + q * 256 + (j & 255)];
        }
        // 2) issue the quarter's 16 h loads, NONTEMPORAL (use-once stream)
        f32x4 hv[4][4];  // [k][row]
#pragma unroll
        for (int k = 0; k < 4; ++k)
#pragma unroll
            for (int row = 0; row < 4; ++row)
                hv[k][row] = __builtin_nontemporal_load(
                    (const f32x4*)(h + (m0 + r0w + row) * D
                                   + q * 1024 + k * 256 + lane * 4));
        // 3) LDS write (waits only the stage loads; h stays in flight)
#pragma unroll
        for (int s = 0; s < 8; ++s) dst[s * 256 + tid] = sreg[s];
        __syncthreads();
        // 4) compute from registers + LDS broadcasts
#pragma unroll
        for (int k = 0; k < 4; ++k) {
            const int il = k * 256 + lane * 4;
            f32x4 wbv[RANK];
#pragma unroll
            for (int r = 0; r < RANK; ++r)
                wbv[r] = *(const f32x4*)&wbs[r][il];
#pragma unroll
            for (int row = 0; row < 4; ++row)
#pragma unroll
                for (int r = 0; r < RANK; ++r)
                    acc[row][r] = fmaf(hv[k][row].x, wbv[r].x,
                                  fmaf(hv[k][row].y, wbv[r].y,
                                  fmaf(hv[k][row].z, wbv[r].z,
                                  fmaf(hv[k][row].w, wbv[r].w, acc[row][r]))));
        }
    }

    // butterfly reduce over lanes; lane0 stores t (tiny write)
#pragma unroll
    for (int row = 0; row < 4; ++row)
#pragma unroll
        for (int r = 0; r < RANK; ++r)
#pragma unroll
            for (int off = 32; off; off >>= 1)
                acc[row][r] += __shfl_xor(acc[row][r], off, 64);
    if (lane == 0) {
#pragma unroll
        for (int row = 0; row < 4; ++row) {
            const f32x4 v0 = {acc[row][0], acc[row][1], acc[row][2], acc[row][3]};
            const f32x4 v1 = {acc[row][4], acc[row][5], acc[row][6], acc[row][7]};
            f32x4* __restrict__ dt = (f32x4*)(t + (m0 + r0w + row) * RANK);
            dt[0] = v0; dt[1] = v1;
        }
    }
}

// ---------------------------------------------------------------------------
// Kernel O (R16-exact, best measured): out[m][o] = sum_r t[m][r]*wa[o][r].
// 64 rows/block, plain stores, 512 blocks.
// ---------------------------------------------------------------------------
__global__ __launch_bounds__(256) void k_o(
    const float* __restrict__ t,
    const float* __restrict__ wa1, const float* __restrict__ wa2,
    const unsigned* __restrict__ hdr,
    float* __restrict__ out) {
    const int tid = threadIdx.x;
    const int wave = tid >> 6, lane = tid & 63;
    const float* __restrict__ wa = hdr[4] ? wa1 : wa2;
    const int cslice = blockIdx.x & 3;               // which 1024-col slice
    const size_t m0 = (size_t)(blockIdx.x >> 2) * 64;
    const int o0 = cslice * 1024 + wave * 256 + lane * 4;

    __shared__ float ts[64][8];  // 2 KB t tile
    if (tid < 128)
        ((f32x4*)ts)[tid] = *(const f32x4*)(t + m0 * RANK + tid * 4);

    f32x4 A[8];  // wa for this lane's 4 cols: A[2j]=col(o0+j) r0..3, A[2j+1]=r4..7
#pragma unroll
    for (int j = 0; j < 8; ++j)
        A[j] = *(const f32x4*)(wa + (size_t)o0 * RANK + j * 4);
    __syncthreads();

#pragma unroll 4
    for (int row = 0; row < 64; ++row) {
        const f32x4 t03 = *(const f32x4*)&ts[row][0];
        const f32x4 t47 = *(const f32x4*)&ts[row][4];
        f32x4 ov;
        ov.x = dot4v(A[0], t03) + dot4v(A[1], t47);
        ov.y = dot4v(A[2], t03) + dot4v(A[3], t47);
        ov.z = dot4v(A[4], t03) + dot4v(A[5], t47);
        ov.w = dot4v(A[6], t03) + dot4v(A[7], t47);
        *(f32x4*)(out + (m0 + row) * D + o0) = ov;  // plain store
    }
}

extern "C" void kernel_launch(void* const* d_in, const int* in_sizes, int n_in,
                              void* d_out, int out_size, void* d_ws, size_t ws_size,
                              hipStream_t stream) {
    const float* h   = (const float*)d_in[0];
    const float* wa1 = (const float*)d_in[1];
    const float* wb1 = (const float*)d_in[2];
    const float* wa2 = (const float*)d_in[3];
    const float* wb2 = (const float*)d_in[4];
    const int*   ts  = (const int*)d_in[5];
    float* out = (float*)d_out;

    const int rows = in_sizes[0] / D;  // 8192

    unsigned* hdr  = (unsigned*)d_ws;
    unsigned* gcnt = (unsigned*)((char*)d_ws + WS_GCNT_OFF);
    unsigned long long* gsum = (unsigned long long*)((char*)d_ws + WS_GSUM_OFF);
    unsigned* bmax = (unsigned*)((char*)d_ws + WS_BMAX_OFF);
    float*    tbuf = (float*)((char*)d_ws + WS_T_OFF);

    hipLaunchKernelGGL(k_pass_max, dim3(256, 2), dim3(256), 0, stream,
                       wa1, wb1, wa2, wb2, gcnt, bmax);
    hipLaunchKernelGGL(k_pass_hist, dim3(256, 2), dim3(256), 0, stream,
                       wa1, wb1, wa2, wb2, bmax, gcnt, gsum);
    hipLaunchKernelGGL(k_select, dim3(1), dim3(1024), 0, stream,
                       hdr, bmax, gcnt, gsum, ts);
    hipLaunchKernelGGL(k_t, dim3(rows / 16), dim3(256), 0, stream,
                       h, wb1, wb2, hdr, tbuf);
    hipLaunchKernelGGL(k_o, dim3(4 * (rows / 64)), dim3(256), 0, stream,
                       tbuf, wa1, wa2, hdr, out);
}

// Round 19
// 90.937 us; speedup vs baseline: 1.1132x; 1.0822x over previous
//
#include <hip/hip_runtime.h>
#include <stdint.h>

#define D 4096
#define RANK 8
#define ALPHA 1.5f
#define BETA 0.5f
#define SUM_TIMESTEPS 28000
#define K_TOP 64
#define NBINS 1024

typedef float f32x4 __attribute__((ext_vector_type(4)));

// ws layout (bytes):
//   [0, 256)            : u32 hdr[]: [4]=flag (written unconditionally each call)
//   [256, 256+8K)       : u32 gcnt[2][NBINS]   (zeroed by k_pass_max each call)
//   [8448, 8448+16K)    : u64 gsum[2][NBINS]   (zeroed by k_pass_max each call)
//   [24832, 24832+2K)   : u32 bmax[2][256]     (written unconditionally each call)
//   [26880, +256K)      : f32 t[8192][8]       (written unconditionally each call)
#define WS_GCNT_OFF 256
#define WS_GSUM_OFF (256 + 2 * NBINS * 4)
#define WS_BMAX_OFF (WS_GSUM_OFF + 2 * NBINS * 8)
#define WS_T_OFF    (WS_BMAX_OFF + 2048)

// fixed-point scale: 2^38 / max  (sum of 16.7M maximal values still < 2^62)
#define FIX_NUM 2.74877906944e11f
#define FIX_INV 3.637978807091713e-12   // 2^-38

__device__ __forceinline__ float dot4v(f32x4 a, f32x4 b) {
    return fmaf(a.x, b.x, fmaf(a.y, b.y, fmaf(a.z, b.z, a.w * b.w)));
}

// ---------------------------------------------------------------------------
// Pass 1: per-block max of |wa@wb| -> bmax[mat][bid]. wa slice staged in LDS.
// Zeroes gcnt/gsum for the NEXT kernel. grid (256, 2), block 256.
// ---------------------------------------------------------------------------
__global__ __launch_bounds__(256) void k_pass_max(
    const float* __restrict__ wa1, const float* __restrict__ wb1,
    const float* __restrict__ wa2, const float* __restrict__ wb2,
    unsigned* __restrict__ gz, unsigned* __restrict__ bmax) {
    const int tid = threadIdx.x;
    const int mat = blockIdx.y;
    const int bid = blockIdx.x;
    // zero gcnt/gsum stripes (consumed by the NEXT kernel, so no race)
    if (mat == 0 && tid < 24) gz[bid * 24 + tid] = 0u;

    const float* __restrict__ wa = mat ? wa2 : wa1;
    const float* __restrict__ wb = mat ? wb2 : wb1;
    const int i0 = (bid & 3) * 1024 + tid * 4;
    const int obase = (bid >> 2) * 64;

    __shared__ float was[64][8];  // 2 KB wa slice
    if (tid < 128)
        ((f32x4*)was)[tid] = ((const f32x4*)(wa + (size_t)obase * RANK))[tid];

    f32x4 wbv[RANK];
#pragma unroll
    for (int r = 0; r < RANK; ++r)
        wbv[r] = *(const f32x4*)(wb + r * D + i0);
    __syncthreads();

    float vmax = 0.f;
#pragma unroll 4
    for (int oo = 0; oo < 64; ++oo) {
        const f32x4 w03 = *(const f32x4*)&was[oo][0];  // LDS broadcast
        const f32x4 w47 = *(const f32x4*)&was[oo][4];
        f32x4 s = {0.f, 0.f, 0.f, 0.f};
        const float a[8] = {w03.x, w03.y, w03.z, w03.w, w47.x, w47.y, w47.z, w47.w};
#pragma unroll
        for (int r = 0; r < RANK; ++r) {
            s.x = fmaf(a[r], wbv[r].x, s.x);
            s.y = fmaf(a[r], wbv[r].y, s.y);
            s.z = fmaf(a[r], wbv[r].z, s.z);
            s.w = fmaf(a[r], wbv[r].w, s.w);
        }
        vmax = fmaxf(vmax, fmaxf(fmaxf(fabsf(s.x), fabsf(s.y)),
                                 fmaxf(fabsf(s.z), fabsf(s.w))));
    }
    for (int off = 32; off; off >>= 1)
        vmax = fmaxf(vmax, __shfl_xor(vmax, off, 64));
    __shared__ float smax[4];
    const int wave = tid >> 6, lane = tid & 63;
    if (lane == 0) smax[wave] = vmax;
    __syncthreads();
    if (tid == 0) {
        float m = fmaxf(fmaxf(smax[0], smax[1]), fmaxf(smax[2], smax[3]));
        bmax[mat * 256 + bid] = __float_as_uint(m);  // unconditional write
    }
}

// ---------------------------------------------------------------------------
// helper: block-level max over 256 bmax entries (block must be >=256 thr)
// ---------------------------------------------------------------------------
__device__ __forceinline__ float block_max256(const unsigned* __restrict__ bmax,
                                              int mat, int tid, float* redm) {
    const int wave = tid >> 6, lane = tid & 63;
    float m = 0.f;
    if (tid < 256) m = __uint_as_float(bmax[mat * 256 + tid]);
    for (int off = 32; off; off >>= 1)
        m = fmaxf(m, __shfl_xor(m, off, 64));
    if (tid < 256 && lane == 0) redm[wave] = m;
    __syncthreads();
    return fmaxf(fmaxf(redm[0], redm[1]), fmaxf(redm[2], redm[3]));
}

// ---------------------------------------------------------------------------
// Pass 2: histogram all |elem| >= 0.5*max. Counts u32, sums u64 fixed-point
// (order-independent integer atomics -> bit-deterministic across replays).
// wa slice staged in LDS. grid (256, 2), block 256.
// ---------------------------------------------------------------------------
__global__ __launch_bounds__(256) void k_pass_hist(
    const float* __restrict__ wa1, const float* __restrict__ wb1,
    const float* __restrict__ wa2, const float* __restrict__ wb2,
    const unsigned* __restrict__ bmax,
    unsigned* __restrict__ gcnt, unsigned long long* __restrict__ gsum) {
    __shared__ unsigned lcnt[NBINS];
    __shared__ unsigned long long lsum[NBINS];
    __shared__ float was[64][8];
    __shared__ float redm[4];
    const int tid = threadIdx.x;
    const int mat = blockIdx.y;
    for (int b = tid; b < NBINS; b += 256) { lcnt[b] = 0u; lsum[b] = 0ull; }

    const float* __restrict__ wa = mat ? wa2 : wa1;
    const float* __restrict__ wb = mat ? wb2 : wb1;
    const int i0 = (blockIdx.x & 3) * 1024 + tid * 4;
    const int obase = (blockIdx.x >> 2) * 64;
    if (tid < 128)
        ((f32x4*)was)[tid] = ((const f32x4*)(wa + (size_t)obase * RANK))[tid];

    // (block_max256 contains the needed barrier)
    const float M = block_max256(bmax, mat, tid, redm);
    const float T = 0.5f * M;
    const float fix = FIX_NUM / M;
    const unsigned bitsT = __float_as_uint(T);

    f32x4 wbv[RANK];
#pragma unroll
    for (int r = 0; r < RANK; ++r)
        wbv[r] = *(const f32x4*)(wb + r * D + i0);

#pragma unroll 2
    for (int oo = 0; oo < 64; ++oo) {
        const f32x4 w03 = *(const f32x4*)&was[oo][0];
        const f32x4 w47 = *(const f32x4*)&was[oo][4];
        f32x4 s = {0.f, 0.f, 0.f, 0.f};
        const float a[8] = {w03.x, w03.y, w03.z, w03.w, w47.x, w47.y, w47.z, w47.w};
#pragma unroll
        for (int r = 0; r < RANK; ++r) {
            s.x = fmaf(a[r], wbv[r].x, s.x);
            s.y = fmaf(a[r], wbv[r].y, s.y);
            s.z = fmaf(a[r], wbv[r].z, s.z);
            s.w = fmaf(a[r], wbv[r].w, s.w);
        }
        const float av[4] = {fabsf(s.x), fabsf(s.y), fabsf(s.z), fabsf(s.w)};
#pragma unroll
        for (int j = 0; j < 4; ++j) {
            if (av[j] >= T) {
                unsigned k = (__float_as_uint(av[j]) - bitsT) >> 13;
                if (k > NBINS - 1u) k = NBINS - 1u;
                atomicAdd(&lcnt[k], 1u);
                atomicAdd(&lsum[k], (unsigned long long)(av[j] * fix));
            }
        }
    }
    __syncthreads();
    unsigned* __restrict__ gc = gcnt + (size_t)mat * NBINS;
    unsigned long long* __restrict__ gs = gsum + (size_t)mat * NBINS;
    for (int b = tid; b < NBINS; b += 256) {
        unsigned c = lcnt[b];
        if (c) {
            atomicAdd(&gc[b], c);
            atomicAdd(&gs[b], lsum[b]);
        }
    }
}

// ---------------------------------------------------------------------------
// Pass 3: one block, 1024 threads; suffix-scan histogram (integer, exact),
// top-64 cutoff, flag. Fully deterministic.
// ---------------------------------------------------------------------------
__global__ __launch_bounds__(1024) void k_select(
    unsigned* __restrict__ hdr, const unsigned* __restrict__ bmax,
    const unsigned* __restrict__ gcnt, const unsigned long long* __restrict__ gsum,
    const int* __restrict__ tsp) {
    __shared__ unsigned sc[NBINS];
    __shared__ unsigned long long ss[NBINS];
    __shared__ float res[2];
    __shared__ float Ms[2];
    __shared__ float redm[4];
    __shared__ int sB;
    const int b = threadIdx.x;

    for (int mat = 0; mat < 2; ++mat) {
        float M = block_max256(bmax, mat, b, redm);
        if (b == 0) Ms[mat] = M;
        __syncthreads();
    }

    for (int mat = 0; mat < 2; ++mat) {
        if (b == 0) sB = -1;
        const unsigned c0 = gcnt[(size_t)mat * NBINS + b];
        const unsigned long long s0 = gsum[(size_t)mat * NBINS + b];
        __syncthreads();           // previous iteration's readers done
        sc[b] = c0;
        ss[b] = s0;
        __syncthreads();
        // Hillis-Steele suffix scan (integer adds: exact, order-independent)
        for (int step = 1; step < NBINS; step <<= 1) {
            unsigned c2 = 0u; unsigned long long s2 = 0ull;
            if (b + step < NBINS) { c2 = sc[b + step]; s2 = ss[b + step]; }
            __syncthreads();
            sc[b] += c2;
            ss[b] += s2;
            __syncthreads();
        }
        if (sc[b] >= K_TOP && (b == NBINS - 1 || sc[b + 1] < K_TOP)) sB = b;
        __syncthreads();
        if (b == 0) {
            const double inv = (double)Ms[mat] * FIX_INV;  // decode units -> value
            float total;
            if (sB < 0) {
                total = (float)((double)ss[0] * inv);
            } else {
                const int B = sB;
                const unsigned cAbove = (B + 1 < NBINS) ? sc[B + 1] : 0u;
                const unsigned long long sAbove = (B + 1 < NBINS) ? ss[B + 1] : 0ull;
                const unsigned cb = sc[B] - cAbove;
                const unsigned long long sb = ss[B] - sAbove;
                const unsigned need = K_TOP - cAbove;
                total = (float)((double)sAbove * inv)
                      + (float)((double)sb * inv) * ((float)need / (float)cb);
            }
            res[mat] = total;
        }
        __syncthreads();
    }
    if (b == 0) {
        const int tr = (*tsp) % SUM_TIMESTEPS;
        const float scale = fmodf(ALPHA * (float)tr / (float)SUM_TIMESTEPS + BETA, ALPHA);
        const float temp_ratio = res[0] / (res[1] * scale);  // AVG_RATIO = 1.0
        hdr[4] = (temp_ratio > 1.0f) ? 1u : 0u;              // 1 -> matrix1
    }
}

// ---------------------------------------------------------------------------
// Kernel T (R16-exact best measured): t[m][r] = sum_i h[m,i]*wb[r,i].
// Block = 256 thr (4 waves), 8 rows, grid 1024. wb staged in 32 KB LDS
// quarters; h loads NONTEMPORAL, issued into registers before the
// ds_write+barrier.
// ---------------------------------------------------------------------------
__global__ __launch_bounds__(256) void k_t(
    const float* __restrict__ h,
    const float* __restrict__ wb1, const float* __restrict__ wb2,
    const unsigned* __restrict__ hdr,
    float* __restrict__ t) {
    const int tid = threadIdx.x;
    const int wave = tid >> 6, lane = tid & 63;
    const float* __restrict__ wb = hdr[4] ? wb1 : wb2;
    const size_t m0 = (size_t)blockIdx.x * 8;
    const int r0w = wave * 2;  // this wave's 2 local rows

    __shared__ float wbs[RANK][1024];  // 32 KB: quarter of wb

    float acc[2][RANK];
#pragma unroll
    for (int row = 0; row < 2; ++row)
#pragma unroll
        for (int r = 0; r < RANK; ++r) acc[row][r] = 0.f;

    const f32x4* __restrict__ src = (const f32x4*)wb;  // row stride 1024 f32x4
    f32x4* __restrict__ dst = (f32x4*)wbs;

    for (int q = 0; q < 4; ++q) {
        __syncthreads();  // previous quarter's readers done
        // 1) issue stage loads (8 x f32x4, CACHED: reused by 1024 blocks)
        f32x4 sreg[8];
#pragma unroll
        for (int s = 0; s < 8; ++s) {
            const int j = s * 256 + tid;   // [0, 2048)
            sreg[s] = src[(j >> 8) * 1024 + q * 256 + (j & 255)];
        }
        // 2) issue the quarter's 8 h loads, NONTEMPORAL (use-once stream)
        f32x4 hv[4][2];  // [k][row]
#pragma unroll
        for (int k = 0; k < 4; ++k)
#pragma unroll
            for (int row = 0; row < 2; ++row)
                hv[k][row] = __builtin_nontemporal_load(
                    (const f32x4*)(h + (m0 + r0w + row) * D
                                   + q * 1024 + k * 256 + lane * 4));
        // 3) LDS write (waits only the stage loads; h stays in flight)
#pragma unroll
        for (int s = 0; s < 8; ++s) dst[s * 256 + tid] = sreg[s];
        __syncthreads();
        // 4) compute from registers + LDS broadcasts
#pragma unroll
        for (int k = 0; k < 4; ++k) {
            const int il = k * 256 + lane * 4;
            f32x4 wbv[RANK];
#pragma unroll
            for (int r = 0; r < RANK; ++r)
                wbv[r] = *(const f32x4*)&wbs[r][il];
#pragma unroll
            for (int row = 0; row < 2; ++row)
#pragma unroll
                for (int r = 0; r < RANK; ++r)
                    acc[row][r] = fmaf(hv[k][row].x, wbv[r].x,
                                  fmaf(hv[k][row].y, wbv[r].y,
                                  fmaf(hv[k][row].z, wbv[r].z,
                                  fmaf(hv[k][row].w, wbv[r].w, acc[row][r]))));
        }
    }

    // butterfly reduce over lanes; lane0 stores t (tiny write)
#pragma unroll
    for (int row = 0; row < 2; ++row)
#pragma unroll
        for (int r = 0; r < RANK; ++r)
#pragma unroll
            for (int off = 32; off; off >>= 1)
                acc[row][r] += __shfl_xor(acc[row][r], off, 64);
    if (lane == 0) {
#pragma unroll
        for (int row = 0; row < 2; ++row)
#pragma unroll
            for (int r = 0; r < RANK; ++r)
                t[(m0 + r0w + row) * RANK + r] = acc[row][r];
    }
}

// ---------------------------------------------------------------------------
// Kernel O (R16-exact best measured): out[m][o] = sum_r t[m][r]*wa[o][r].
// 64 rows/block, plain stores, 512 blocks.
// ---------------------------------------------------------------------------
__global__ __launch_bounds__(256) void k_o(
    const float* __restrict__ t,
    const float* __restrict__ wa1, const float* __restrict__ wa2,
    const unsigned* __restrict__ hdr,
    float* __restrict__ out) {
    const int tid = threadIdx.x;
    const int wave = tid >> 6, lane = tid & 63;
    const float* __restrict__ wa = hdr[4] ? wa1 : wa2;
    const int cslice = blockIdx.x & 3;               // which 1024-col slice
    const size_t m0 = (size_t)(blockIdx.x >> 2) * 64;
    const int o0 = cslice * 1024 + wave * 256 + lane * 4;

    __shared__ float ts[64][8];  // 2 KB t tile
    if (tid < 128)
        ((f32x4*)ts)[tid] = *(const f32x4*)(t + m0 * RANK + tid * 4);

    f32x4 A[8];  // wa for this lane's 4 cols: A[2j]=col(o0+j) r0..3, A[2j+1]=r4..7
#pragma unroll
    for (int j = 0; j < 8; ++j)
        A[j] = *(const f32x4*)(wa + (size_t)o0 * RANK + j * 4);
    __syncthreads();

#pragma unroll 4
    for (int row = 0; row < 64; ++row) {
        const f32x4 t03 = *(const f32x4*)&ts[row][0];
        const f32x4 t47 = *(const f32x4*)&ts[row][4];
        f32x4 ov;
        ov.x = dot4v(A[0], t03) + dot4v(A[1], t47);
        ov.y = dot4v(A[2], t03) + dot4v(A[3], t47);
        ov.z = dot4v(A[4], t03) + dot4v(A[5], t47);
        ov.w = dot4v(A[6], t03) + dot4v(A[7], t47);
        *(f32x4*)(out + (m0 + row) * D + o0) = ov;  // plain store
    }
}

extern "C" void kernel_launch(void* const* d_in, const int* in_sizes, int n_in,
                              void* d_out, int out_size, void* d_ws, size_t ws_size,
                              hipStream_t stream) {
    const float* h   = (const float*)d_in[0];
    const float* wa1 = (const float*)d_in[1];
    const float* wb1 = (const float*)d_in[2];
    const float* wa2 = (const float*)d_in[3];
    const float* wb2 = (const float*)d_in[4];
    const int*   ts  = (const int*)d_in[5];
    float* out = (float*)d_out;

    const int rows = in_sizes[0] / D;  // 8192

    unsigned* hdr  = (unsigned*)d_ws;
    unsigned* gcnt = (unsigned*)((char*)d_ws + WS_GCNT_OFF);
    unsigned long long* gsum = (unsigned long long*)((char*)d_ws + WS_GSUM_OFF);
    unsigned* bmax = (unsigned*)((char*)d_ws + WS_BMAX_OFF);
    float*    tbuf = (float*)((char*)d_ws + WS_T_OFF);

    hipLaunchKernelGGL(k_pass_max, dim3(256, 2), dim3(256), 0, stream,
                       wa1, wb1, wa2, wb2, gcnt, bmax);
    hipLaunchKernelGGL(k_pass_hist, dim3(256, 2), dim3(256), 0, stream,
                       wa1, wb1, wa2, wb2, bmax, gcnt, gsum);
    hipLaunchKernelGGL(k_select, dim3(1), dim3(1024), 0, stream,
                       hdr, bmax, gcnt, gsum, ts);
    hipLaunchKernelGGL(k_t, dim3(rows / 8), dim3(256), 0, stream,
                       h, wb1, wb2, hdr, tbuf);
    hipLaunchKernelGGL(k_o, dim3(4 * (rows / 64)), dim3(256), 0, stream,
                       tbuf, wa1, wa2, hdr, out);
}